// Round 1
// baseline (30.733 us; speedup 1.0000x reference)
//
#include <hip/hip_runtime.h>

#define NEG_INF -9.0e15f

__device__ __forceinline__ int swz(int row) { return (row ^ (row >> 3)) & 7; }

__device__ __forceinline__ float f4c(const float4& v, int w) {
    return w == 0 ? v.x : w == 1 ? v.y : w == 2 ? v.z : v.w;
}

__global__ __launch_bounds__(256, 1) void gat_kernel(
    const float* __restrict__ h,
    const int*   __restrict__ adj,
    const float* __restrict__ a0,
    const float* __restrict__ a1,
    const float* __restrict__ a2,
    const float* __restrict__ a3,
    float* __restrict__ out)
{
    constexpr int N = 128, D = 128;
    __shared__ float sh[N * D];       // 64 KB: h[b], per-row chunk-swizzled
    __shared__ float sal[32 * 132];   // alpha rows, padded stride 132

    const int tid = threadIdx.x;
    const int b   = blockIdx.x >> 2;
    const int i0  = (blockIdx.x & 3) * 32;

    const float* __restrict__ hb = h + (size_t)b * N * D;

    // ---- stage h[b] -> LDS (reg-staged so we can swizzle; coalesced global reads) ----
    {
        const float4* __restrict__ src = reinterpret_cast<const float4*>(hb);
        #pragma unroll
        for (int w = 0; w < 16; ++w) {
            int gc  = w * 256 + tid;        // chunk id, 32 chunks/row
            int row = gc >> 5;
            int c   = gc & 31;
            float4 v = src[gc];
            *reinterpret_cast<float4*>(&sh[row * D + ((c ^ swz(row)) << 2)]) = v;
        }
    }
    __syncthreads();

    // ---- phase 1: scores. thread (ti,tj) owns i in {ra,ra+1}, j in [jb, jb+8) ----
    const int tj = tid & 15;
    const int ti = tid >> 4;
    const int jb = tj * 8;
    const int ra = i0 + 2 * ti;

    float acc[2][8][4];
    #pragma unroll
    for (int ii = 0; ii < 2; ++ii)
        #pragma unroll
        for (int jj = 0; jj < 8; ++jj)
            #pragma unroll
            for (int k = 0; k < 4; ++k) acc[ii][jj][k] = 0.f;

    const int si0 = swz(ra), si1 = swz(ra + 1);
    const int ro0 = ra * D, ro1 = (ra + 1) * D;
    int rj_off[8], sj[8];
    #pragma unroll
    for (int jj = 0; jj < 8; ++jj) { rj_off[jj] = (jb + jj) * D; sj[jj] = swz(jb + jj); }

    const float4* __restrict__ A0 = reinterpret_cast<const float4*>(a0);
    const float4* __restrict__ A1 = reinterpret_cast<const float4*>(a1);
    const float4* __restrict__ A2 = reinterpret_cast<const float4*>(a2);
    const float4* __restrict__ A3 = reinterpret_cast<const float4*>(a3);

    #pragma unroll 4
    for (int c = 0; c < 32; ++c) {
        float4 av0 = A0[c], av1 = A1[c], av2 = A2[c], av3 = A3[c];  // wave-uniform -> s_load
        float4 hi0 = *reinterpret_cast<const float4*>(&sh[ro0 + ((c ^ si0) << 2)]);
        float4 hi1 = *reinterpret_cast<const float4*>(&sh[ro1 + ((c ^ si1) << 2)]);
        float4 hj[8];
        #pragma unroll
        for (int jj = 0; jj < 8; ++jj)
            hj[jj] = *reinterpret_cast<const float4*>(&sh[rj_off[jj] + ((c ^ sj[jj]) << 2)]);

        #pragma unroll
        for (int w = 0; w < 4; ++w) {
            float aw0 = f4c(av0, w), aw1 = f4c(av1, w), aw2 = f4c(av2, w), aw3 = f4c(av3, w);
            float h0 = f4c(hi0, w), h1 = f4c(hi1, w);
            #pragma unroll
            for (int jj = 0; jj < 8; ++jj) {
                float hw = f4c(hj[jj], w);
                float p0 = h0 * hw;
                float p1 = h1 * hw;
                acc[0][jj][0] = fmaf(p0, aw0, acc[0][jj][0]);
                acc[0][jj][1] = fmaf(p0, aw1, acc[0][jj][1]);
                acc[0][jj][2] = fmaf(p0, aw2, acc[0][jj][2]);
                acc[0][jj][3] = fmaf(p0, aw3, acc[0][jj][3]);
                acc[1][jj][0] = fmaf(p1, aw0, acc[1][jj][0]);
                acc[1][jj][1] = fmaf(p1, aw1, acc[1][jj][1]);
                acc[1][jj][2] = fmaf(p1, aw2, acc[1][jj][2]);
                acc[1][jj][3] = fmaf(p1, aw3, acc[1][jj][3]);
            }
        }
    }

    // ---- select by adj code, leaky-relu, mask ----
    float sc[2][8];
    #pragma unroll
    for (int ii = 0; ii < 2; ++ii) {
        const int4* ap = reinterpret_cast<const int4*>(adj + ((size_t)b * N + (ra + ii)) * N + jb);
        int4 k0 = ap[0], k1 = ap[1];
        int kv[8] = {k0.x, k0.y, k0.z, k0.w, k1.x, k1.y, k1.z, k1.w};
        #pragma unroll
        for (int jj = 0; jj < 8; ++jj) {
            int k = kv[jj];
            float v = (k == 1) ? acc[ii][jj][0] :
                      (k == 2) ? acc[ii][jj][1] :
                      (k == 3) ? acc[ii][jj][2] :
                      (k == 4) ? acc[ii][jj][3] : 0.f;
            v = (v > 0.f) ? v : 0.2f * v;          // leaky relu, slope 0.2
            sc[ii][jj] = (k == 0) ? NEG_INF : v;
        }
    }

    // ---- phase 2: softmax over j (16 tj-lanes x 8 vals), write alpha to LDS ----
    #pragma unroll
    for (int ii = 0; ii < 2; ++ii) {
        float m = sc[ii][0];
        #pragma unroll
        for (int jj = 1; jj < 8; ++jj) m = fmaxf(m, sc[ii][jj]);
        #pragma unroll
        for (int mk = 1; mk < 16; mk <<= 1) m = fmaxf(m, __shfl_xor(m, mk));
        float p[8];
        float sum = 0.f;
        #pragma unroll
        for (int jj = 0; jj < 8; ++jj) { p[jj] = __expf(sc[ii][jj] - m); sum += p[jj]; }
        #pragma unroll
        for (int mk = 1; mk < 16; mk <<= 1) sum += __shfl_xor(sum, mk);
        float r = 1.0f / sum;
        float4 w0 = make_float4(p[0] * r, p[1] * r, p[2] * r, p[3] * r);
        float4 w1 = make_float4(p[4] * r, p[5] * r, p[6] * r, p[7] * r);
        float4* dst = reinterpret_cast<float4*>(&sal[(2 * ti + ii) * 132 + jb]);
        dst[0] = w0;
        dst[1] = w1;
    }
    __syncthreads();

    // ---- phase 3: out[i, :] = alpha[i, :] @ h.  thread (ti2, td): rows {r0,r0+1},
    //      d in {4*td..4*td+3} U {64+4*td..64+4*td+3} (chunk split avoids bank conflicts) ----
    const int td  = tid & 15;
    const int ti2 = tid >> 4;
    const int r0  = 2 * ti2;

    float oa[2][8];
    #pragma unroll
    for (int ii = 0; ii < 2; ++ii)
        #pragma unroll
        for (int w = 0; w < 8; ++w) oa[ii][w] = 0.f;

    const float* arow0 = &sal[r0 * 132];
    const float* arow1 = &sal[(r0 + 1) * 132];

    #pragma unroll 2
    for (int jq = 0; jq < 32; ++jq) {
        float4 al0 = *reinterpret_cast<const float4*>(arow0 + jq * 4);
        float4 al1 = *reinterpret_cast<const float4*>(arow1 + jq * 4);
        #pragma unroll
        for (int jj = 0; jj < 4; ++jj) {
            int j = jq * 4 + jj;
            int s = swz(j);
            const float* rj = &sh[j * D];
            float4 hv0 = *reinterpret_cast<const float4*>(rj + ((td ^ s) << 2));
            float4 hv1 = *reinterpret_cast<const float4*>(rj + (((td + 16) ^ s) << 2));
            float aa0 = f4c(al0, jj), aa1 = f4c(al1, jj);
            #pragma unroll
            for (int w = 0; w < 4; ++w) {
                oa[0][w]     = fmaf(aa0, f4c(hv0, w), oa[0][w]);
                oa[0][4 + w] = fmaf(aa0, f4c(hv1, w), oa[0][4 + w]);
                oa[1][w]     = fmaf(aa1, f4c(hv0, w), oa[1][w]);
                oa[1][4 + w] = fmaf(aa1, f4c(hv1, w), oa[1][4 + w]);
            }
        }
    }

    float* ob = out + ((size_t)b * N + (i0 + r0)) * D;
    *reinterpret_cast<float4*>(&ob[td * 4])          = make_float4(oa[0][0], oa[0][1], oa[0][2], oa[0][3]);
    *reinterpret_cast<float4*>(&ob[64 + td * 4])     = make_float4(oa[0][4], oa[0][5], oa[0][6], oa[0][7]);
    *reinterpret_cast<float4*>(&ob[D + td * 4])      = make_float4(oa[1][0], oa[1][1], oa[1][2], oa[1][3]);
    *reinterpret_cast<float4*>(&ob[D + 64 + td * 4]) = make_float4(oa[1][4], oa[1][5], oa[1][6], oa[1][7]);
}

extern "C" void kernel_launch(void* const* d_in, const int* in_sizes, int n_in,
                              void* d_out, int out_size, void* d_ws, size_t ws_size,
                              hipStream_t stream) {
    const float* h  = (const float*)d_in[0];
    const int*   adj = (const int*)d_in[1];
    const float* a0 = (const float*)d_in[2];
    const float* a1 = (const float*)d_in[3];
    const float* a2 = (const float*)d_in[4];
    const float* a3 = (const float*)d_in[5];
    float* out = (float*)d_out;
    gat_kernel<<<dim3(256), dim3(256), 0, stream>>>(h, adj, a0, a1, a2, a3, out);
}

// Round 2
// 17.157 us; speedup vs baseline: 1.7913x; 1.7913x over previous
//
#include <hip/hip_runtime.h>

typedef short short8 __attribute__((ext_vector_type(8)));
typedef float floatx4 __attribute__((ext_vector_type(4)));

#define NEG_INF -9.0e15f

// f32 -> bf16, round-half-up (1 ulp-ish, cheap: 2 VALU)
__device__ __forceinline__ unsigned short f2bf(float x) {
    unsigned int u = __float_as_uint(x);
    return (unsigned short)((u + 0x8000u) >> 16);
}

__global__ __launch_bounds__(256, 2) void gat_main(
    const float* __restrict__ h,
    const int*   __restrict__ adj,
    const float* __restrict__ a0,
    const float* __restrict__ a1,
    const float* __restrict__ a2,
    const float* __restrict__ a3,
    float* __restrict__ out)
{
    // chunk-XOR swizzled bf16 tiles: element (row, col) lives at
    // row*128 + ((( (col>>3) ^ (row&7) ) << 3) | (col&7))
    __shared__ __align__(16) unsigned short h_lds [128 * 128]; // [j][d]  32 KB
    __shared__ __align__(16) unsigned short hT_lds[128 * 128]; // [d][j]  32 KB
    __shared__ __align__(16) unsigned short al_lds[16 * 128];  // [i_loc][j] 4 KB
    __shared__ __align__(16) float          red_lds[16 * 8];   // [row][wave][{pm,ps}]

    const int tid = threadIdx.x;
    const int b   = blockIdx.x >> 3;
    const int i0  = (blockIdx.x & 7) << 4;       // 16-row i-strip
    const float* __restrict__ hb = h + ((size_t)b << 14);

    const int w    = tid >> 6;                   // wave 0..3
    const int lane = tid & 63;
    const int c    = lane & 15;                  // MFMA "lane&15" index
    const int g    = lane >> 4;                  // MFMA "lane>>4" index

    // ---- stage h_lds: bf16 row-major, chunk-swizzled ----
    {
        const float4* src = reinterpret_cast<const float4*>(hb);
        #pragma unroll
        for (int it = 0; it < 16; ++it) {
            int id  = (it << 8) + tid;           // 0..4095 float4 chunks
            int row = id >> 5, c4 = id & 31;
            float4 v = src[id];
            short4 pk;
            pk.x = (short)f2bf(v.x); pk.y = (short)f2bf(v.y);
            pk.z = (short)f2bf(v.z); pk.w = (short)f2bf(v.w);
            int idx = row * 128 + (((c4 >> 1) ^ (row & 7)) << 3) + ((c4 & 1) << 2);
            *reinterpret_cast<short4*>(&h_lds[idx]) = pk;
        }
    }
    // ---- stage hT_lds: thread owns column d = tid&127, j-half = tid>>7 ----
    {
        const int d  = tid & 127;
        const int jh = tid >> 7;
        #pragma unroll
        for (int q8 = 0; q8 < 8; ++q8) {
            int jbase = (jh << 6) + (q8 << 3);
            short8 pk;
            #pragma unroll
            for (int e = 0; e < 8; ++e)
                pk[e] = (short)f2bf(hb[(size_t)(jbase + e) * 128 + d]);
            int idx = d * 128 + ((((jh << 3) + q8) ^ (d & 7)) << 3);
            *reinterpret_cast<short8*>(&hT_lds[idx]) = pk;
        }
    }

    // ---- G fragments in registers: G_k[i,d] = h[i,d]*A[d,k] (fp32 mul, one bf16 rounding) ----
    short8 gfr[4][4];                            // [k][K-step s]
    {
        const float* aptr[4] = {a0, a1, a2, a3};
        const int irow = i0 + c;
        #pragma unroll
        for (int s = 0; s < 4; ++s) {
            int doff = (s << 5) + (g << 3);
            float hf[8];
            *reinterpret_cast<float4*>(&hf[0]) = *reinterpret_cast<const float4*>(&hb[irow * 128 + doff]);
            *reinterpret_cast<float4*>(&hf[4]) = *reinterpret_cast<const float4*>(&hb[irow * 128 + doff + 4]);
            #pragma unroll
            for (int k = 0; k < 4; ++k) {
                float af[8];
                *reinterpret_cast<float4*>(&af[0]) = *reinterpret_cast<const float4*>(&aptr[k][doff]);
                *reinterpret_cast<float4*>(&af[4]) = *reinterpret_cast<const float4*>(&aptr[k][doff + 4]);
                short8 pk;
                #pragma unroll
                for (int e = 0; e < 8; ++e) pk[e] = (short)f2bf(hf[e] * af[e]);
                gfr[k][s] = pk;
            }
        }
    }

    // ---- adj prefetch: e-tile positions (i = i0+4g+r, j = (2w+jt)*16+c) ----
    int adjv[2][4];
    #pragma unroll
    for (int jt = 0; jt < 2; ++jt)
        #pragma unroll
        for (int r = 0; r < 4; ++r)
            adjv[jt][r] = adj[((size_t)b << 14) + (size_t)(i0 + (g << 2) + r) * 128
                              + (((2 * w + jt) << 4) + c)];

    __syncthreads();

    // ---- phase 1: e_k tiles via MFMA; wave w owns j-tiles {2w, 2w+1} ----
    floatx4 acc[2][4];
    #pragma unroll
    for (int jt = 0; jt < 2; ++jt)
        #pragma unroll
        for (int k = 0; k < 4; ++k)
            acc[jt][k] = (floatx4){0.f, 0.f, 0.f, 0.f};

    const int jA = ((2 * w) << 4) + c;           // B-operand row (col j of e-tile A)
    const int jB = jA + 16;
    #pragma unroll
    for (int s = 0; s < 4; ++s) {
        int ch = (s << 2) + g;
        short8 bfA = *reinterpret_cast<const short8*>(&h_lds[jA * 128 + ((ch ^ (jA & 7)) << 3)]);
        short8 bfB = *reinterpret_cast<const short8*>(&h_lds[jB * 128 + ((ch ^ (jB & 7)) << 3)]);
        #pragma unroll
        for (int k = 0; k < 4; ++k) {
            acc[0][k] = __builtin_amdgcn_mfma_f32_16x16x32_bf16(gfr[k][s], bfA, acc[0][k], 0, 0, 0);
            acc[1][k] = __builtin_amdgcn_mfma_f32_16x16x32_bf16(gfr[k][s], bfB, acc[1][k], 0, 0, 0);
        }
    }

    // ---- select by relation code + leaky-relu + mask (all in-register) ----
    float sc[2][4], p[2][4], pm[4], ps[4];
    #pragma unroll
    for (int jt = 0; jt < 2; ++jt)
        #pragma unroll
        for (int r = 0; r < 4; ++r) {
            int cd = adjv[jt][r];
            float v = (cd == 1) ? acc[jt][0][r] :
                      (cd == 2) ? acc[jt][1][r] :
                      (cd == 3) ? acc[jt][2][r] : acc[jt][3][r];
            v = (v > 0.f) ? v : 0.2f * v;
            sc[jt][r] = (cd == 0) ? NEG_INF : v;
        }

    // ---- per-wave partial softmax over this wave's 32 j-cols ----
    #pragma unroll
    for (int r = 0; r < 4; ++r) {
        float m = fmaxf(sc[0][r], sc[1][r]);
        #pragma unroll
        for (int mk = 1; mk < 16; mk <<= 1) m = fmaxf(m, __shfl_xor(m, mk));
        float e0 = __expf(sc[0][r] - m);
        float e1 = __expf(sc[1][r] - m);
        float ss = e0 + e1;
        #pragma unroll
        for (int mk = 1; mk < 16; mk <<= 1) ss += __shfl_xor(ss, mk);
        pm[r] = m; ps[r] = ss; p[0][r] = e0; p[1][r] = e1;
    }
    if (c == 0) {
        #pragma unroll
        for (int r = 0; r < 4; ++r) {
            int row = (g << 2) + r;
            red_lds[row * 8 + w * 2]     = pm[r];
            red_lds[row * 8 + w * 2 + 1] = ps[r];
        }
    }
    __syncthreads();

    // ---- combine partials, write alpha (bf16) ----
    #pragma unroll
    for (int r = 0; r < 4; ++r) {
        int row = (g << 2) + r;
        float4 q0 = *reinterpret_cast<const float4*>(&red_lds[row * 8]);
        float4 q1 = *reinterpret_cast<const float4*>(&red_lds[row * 8 + 4]);
        float M = fmaxf(fmaxf(q0.x, q0.z), fmaxf(q1.x, q1.z));
        float S = q0.y * __expf(q0.x - M) + q0.w * __expf(q0.z - M)
                + q1.y * __expf(q1.x - M) + q1.w * __expf(q1.z - M);
        float scale = __expf(pm[r] - M) / S;
        #pragma unroll
        for (int jt = 0; jt < 2; ++jt) {
            int col = ((2 * w + jt) << 4) + c;
            al_lds[row * 128 + (((col >> 3) ^ (row & 7)) << 3) + (col & 7)]
                = f2bf(p[jt][r] * scale);
        }
    }
    __syncthreads();

    // ---- phase 3: out[i,:] = alpha[i,:] @ h ; wave w owns d-tiles {2w, 2w+1} ----
    floatx4 oa[2];
    oa[0] = (floatx4){0.f, 0.f, 0.f, 0.f};
    oa[1] = (floatx4){0.f, 0.f, 0.f, 0.f};
    const int dA = ((2 * w) << 4) + c;
    const int dB = dA + 16;
    #pragma unroll
    for (int s = 0; s < 4; ++s) {
        int ch = (s << 2) + g;
        short8 afr = *reinterpret_cast<const short8*>(&al_lds[c * 128 + ((ch ^ (c & 7)) << 3)]);
        short8 bfA = *reinterpret_cast<const short8*>(&hT_lds[dA * 128 + ((ch ^ (dA & 7)) << 3)]);
        short8 bfB = *reinterpret_cast<const short8*>(&hT_lds[dB * 128 + ((ch ^ (dB & 7)) << 3)]);
        oa[0] = __builtin_amdgcn_mfma_f32_16x16x32_bf16(afr, bfA, oa[0], 0, 0, 0);
        oa[1] = __builtin_amdgcn_mfma_f32_16x16x32_bf16(afr, bfB, oa[1], 0, 0, 0);
    }
    float* ob = out + ((size_t)b << 14);
    #pragma unroll
    for (int di = 0; di < 2; ++di)
        #pragma unroll
        for (int r = 0; r < 4; ++r)
            ob[(size_t)(i0 + (g << 2) + r) * 128 + (((2 * w + di) << 4) + c)] = oa[di][r];
}

extern "C" void kernel_launch(void* const* d_in, const int* in_sizes, int n_in,
                              void* d_out, int out_size, void* d_ws, size_t ws_size,
                              hipStream_t stream) {
    const float* h   = (const float*)d_in[0];
    const int*   adj = (const int*)d_in[1];
    const float* a0  = (const float*)d_in[2];
    const float* a1  = (const float*)d_in[3];
    const float* a2  = (const float*)d_in[4];
    const float* a3  = (const float*)d_in[5];
    float* out = (float*)d_out;
    gat_main<<<dim3(512), dim3(256), 0, stream>>>(h, adj, a0, a1, a2, a3, out);
}